// Round 11
// baseline (231.259 us; speedup 1.0000x reference)
//
#include <hip/hip_runtime.h>
#include <math.h>

#define BGR 32
#define NPER0 1024
#define N0 (BGR * NPER0)
#define FDIM 128
#define EDG 524288
#define EPG (EDG / BGR)   // 16384 edges per graph (contiguous by construction)
#define EBLK (EDG / 256)  // 2048 edge-parallel binning blocks
#define K1 512
#define K2 256
#define K3 128
#define N1 (BGR * K1)
#define N2 (BGR * K2)
#define CAP 64            // slots per node (Poisson(16); P(deg>64) ~ 1e-18)
#define RSEC (BGR * FDIM)

// Order-preserving float<->uint encoding (radix keys + atomicMax readout).
__device__ __forceinline__ unsigned enc_f(float v) {
    unsigned u = __float_as_uint(v);
    return (u & 0x80000000u) ? ~u : (u | 0x80000000u);
}
__device__ __forceinline__ float dec_f(unsigned u) {
    return (u & 0x80000000u) ? __uint_as_float(u ^ 0x80000000u) : __uint_as_float(~u);
}

// ---------------------------------------------------------------------------
// Edge binning (graph-swizzled: graph g's cnt/slot atomics land on XCD g%8,
// where g's aggw also runs). Blocks 0..31 also zero the readout accumulators.
// cnt pre-zeroed by hipMemsetAsync.
// ---------------------------------------------------------------------------
__global__ void bin_kernel(const int* __restrict__ src, const int* __restrict__ dst,
                           int* __restrict__ cnt, int* __restrict__ slot,
                           unsigned* __restrict__ rmax, float* __restrict__ rsum) {
    if (blockIdx.x < BGR) {  // zero readout accumulators: 32*256 == 2*RSEC
        int z = blockIdx.x * 256 + threadIdx.x;
        rmax[z] = 0u;
        rsum[z] = 0.0f;
    }
    const int g = blockIdx.x & 31, chunk = blockIdx.x >> 5;
    int e = g * EPG + chunk * 256 + threadIdx.x;
    int s = src[e];
    int d = dst[e];
    int p = atomicAdd(&cnt[d], 1);
    if (p < CAP) slot[(size_t)d * CAP + p] = s;
}

// ---------------------------------------------------------------------------
// Fused aggregate-then-project kernel (AGG(X)·W == AGG(X·W), both linear).
// R11: TWO nodes per wave (8 per block), edge loops interleaved -> 4 gather
// loads in flight (was 2); W staged once per 8 nodes (was 4). Wave still
// split into 32-lane halves with lane = float4; dummy edges (lanes >= c)
// carry row 0 / coef 0, so both loops run to max(cp0,cp1) branch-free and
// fmaf(v,0,acc) keeps per-node sums bitwise identical to R10.
// ---------------------------------------------------------------------------
__global__ void aggw_kernel(const float* __restrict__ xsrc,
                            const int* __restrict__ permIn,
                            const float* __restrict__ multIn,
                            const int* __restrict__ cnt, const int* __restrict__ slot,
                            const float* __restrict__ W, const float* __restrict__ b,
                            const float* __restrict__ A, const float* __restrict__ psW,
                            float* __restrict__ haOut, float* __restrict__ csd,
                            int nper) {
    __shared__ __align__(16) float sW[4096];
    __shared__ __align__(16) float sY[8][128];
    const int t = threadIdx.x;
    const int w = t >> 6, lane = t & 63;
    const int half = lane >> 5, li = lane & 31;
    const int g = blockIdx.x & 31, chunk = blockIdx.x >> 5;
    const int i0 = g * nper + chunk * 8 + w;   // node A of this wave
    const int i1 = i0 + 4;                      // node B of this wave
    {   // stage W: 4096 floats via float4, coalesced
        float4* d4 = (float4*)sW;
        const float4* s4 = (const float4*)W;
        for (int q = t; q < 1024; q += 256) d4[q] = s4[q];
    }
    const int ci0 = cnt[i0], ci1 = cnt[i1];
    const float di0 = rsqrtf((float)ci0 + 1.0f);
    const float di1 = rsqrtf((float)ci1 + 1.0f);
    const int c0 = min(ci0, CAP), c1 = min(ci1, CAP);
    const float4* __restrict__ x4 = (const float4*)xsrc;
    // self terms (half 0 carries the coefficient; half 1 contributes 0)
    float selfco0 = di0 * di0, selfco1 = di1 * di1;
    size_t selfrow0 = (size_t)i0, selfrow1 = (size_t)i1;
    if (permIn) {
        selfrow0 = (size_t)permIn[i0]; selfco0 *= multIn[i0];
        selfrow1 = (size_t)permIn[i1]; selfco1 *= multIn[i1];
    }
    const float sco0 = half ? 0.0f : selfco0;
    const float sco1 = half ? 0.0f : selfco1;
    float4 sv0 = x4[selfrow0 * 32 + li];
    float4 sv1 = x4[selfrow1 * 32 + li];
    float4 acc0, acc1;
    acc0.x = sv0.x * sco0; acc0.y = sv0.y * sco0;
    acc0.z = sv0.z * sco0; acc0.w = sv0.w * sco0;
    acc1.x = sv1.x * sco1; acc1.y = sv1.y * sco1;
    acc1.z = sv1.z * sco1; acc1.w = sv1.w * sco1;
    // per-lane neighbor prefetch for both nodes (lanes >= c -> row 0 / coef 0)
    int rowA = 0, rowB = 0;
    float codA = 0.0f, codB = 0.0f;
    if (lane < c0) {
        int idx = slot[(size_t)i0 * CAP + lane];
        float dv = rsqrtf((float)cnt[idx] + 1.0f);
        if (permIn) { rowA = permIn[idx]; codA = dv * multIn[idx]; }
        else        { rowA = idx;         codA = dv; }
    }
    if (lane < c1) {
        int idx = slot[(size_t)i1 * CAP + lane];
        float dv = rsqrtf((float)cnt[idx] + 1.0f);
        if (permIn) { rowB = permIn[idx]; codB = dv * multIn[idx]; }
        else        { rowB = idx;         codB = dv; }
    }
    const int cp0 = (c0 + 1) >> 1, cp1 = (c1 + 1) >> 1;
    const int cpm = max(cp0, cp1);   // dummy iterations add exact 0.0
    int p = 0;
    for (; p + 1 < cpm; p += 2) {
        int e0 = 2 * p + half, e1 = e0 + 2;
        int sA0 = __shfl(rowA, e0, 64);
        int sB0 = __shfl(rowB, e0, 64);
        int sA1 = __shfl(rowA, e1, 64);
        int sB1 = __shfl(rowB, e1, 64);
        float cA0 = __shfl(codA, e0, 64) * di0;
        float cB0 = __shfl(codB, e0, 64) * di1;
        float cA1 = __shfl(codA, e1, 64) * di0;
        float cB1 = __shfl(codB, e1, 64) * di1;
        float4 vA0 = x4[(size_t)sA0 * 32 + li];
        float4 vB0 = x4[(size_t)sB0 * 32 + li];
        float4 vA1 = x4[(size_t)sA1 * 32 + li];
        float4 vB1 = x4[(size_t)sB1 * 32 + li];
        acc0.x = fmaf(vA0.x, cA0, acc0.x); acc0.y = fmaf(vA0.y, cA0, acc0.y);
        acc0.z = fmaf(vA0.z, cA0, acc0.z); acc0.w = fmaf(vA0.w, cA0, acc0.w);
        acc1.x = fmaf(vB0.x, cB0, acc1.x); acc1.y = fmaf(vB0.y, cB0, acc1.y);
        acc1.z = fmaf(vB0.z, cB0, acc1.z); acc1.w = fmaf(vB0.w, cB0, acc1.w);
        acc0.x = fmaf(vA1.x, cA1, acc0.x); acc0.y = fmaf(vA1.y, cA1, acc0.y);
        acc0.z = fmaf(vA1.z, cA1, acc0.z); acc0.w = fmaf(vA1.w, cA1, acc0.w);
        acc1.x = fmaf(vB1.x, cB1, acc1.x); acc1.y = fmaf(vB1.y, cB1, acc1.y);
        acc1.z = fmaf(vB1.z, cB1, acc1.z); acc1.w = fmaf(vB1.w, cB1, acc1.w);
    }
    for (; p < cpm; p++) {
        int e = 2 * p + half;
        int sA = __shfl(rowA, e, 64);
        int sB = __shfl(rowB, e, 64);
        float cA = __shfl(codA, e, 64) * di0;
        float cB = __shfl(codB, e, 64) * di1;
        float4 vA = x4[(size_t)sA * 32 + li];
        float4 vB = x4[(size_t)sB * 32 + li];
        acc0.x = fmaf(vA.x, cA, acc0.x); acc0.y = fmaf(vA.y, cA, acc0.y);
        acc0.z = fmaf(vA.z, cA, acc0.z); acc0.w = fmaf(vA.w, cA, acc0.w);
        acc1.x = fmaf(vB.x, cB, acc1.x); acc1.y = fmaf(vB.y, cB, acc1.y);
        acc1.z = fmaf(vB.z, cB, acc1.z); acc1.w = fmaf(vB.w, cB, acc1.w);
    }
    // combine even/odd halves for both nodes
    acc0.x += __shfl_xor(acc0.x, 32, 64);
    acc0.y += __shfl_xor(acc0.y, 32, 64);
    acc0.z += __shfl_xor(acc0.z, 32, 64);
    acc0.w += __shfl_xor(acc0.w, 32, 64);
    acc1.x += __shfl_xor(acc1.x, 32, 64);
    acc1.y += __shfl_xor(acc1.y, 32, 64);
    acc1.z += __shfl_xor(acc1.z, 32, 64);
    acc1.w += __shfl_xor(acc1.w, 32, 64);
    if (half == 0) {
        *(float4*)(&sY[w][li * 4]) = acc0;
        *(float4*)(&sY[w + 4][li * 4]) = acc1;
    }
    __syncthreads();
    // dense per-head W-multiply for both nodes (sY broadcast, sW conflict-free)
    const int f0 = 2 * lane;           // output features f0, f0+1 (same head)
    const int h = f0 >> 5, e0h = f0 & 31;
    const float* wrow = sW + h * 1024 + e0h;
    float2 bb = ((const float2*)b)[lane];
    float2 Av = ((const float2*)A)[lane];
    float2 Pv = ((const float2*)psW)[lane];
#pragma unroll
    for (int nn = 0; nn < 2; nn++) {
        const int node = w + nn * 4;
        const int ii = g * nper + chunk * 8 + node;
        const float di = nn ? di1 : di0;
        const float* yp = sY[node] + h * 32;
        float ax = bb.x, ay = bb.y;
#pragma unroll
        for (int d = 0; d < 32; d++) {
            float yv = yp[d];                              // broadcast read
            float2 wv = *(const float2*)(wrow + d * 32);   // conflict-free
            ax = fmaf(yv, wv.x, ax);
            ay = fmaf(yv, wv.y, ay);
        }
        float2 o;
        o.x = fmaxf(ax, 0.0f);
        o.y = fmaxf(ay, 0.0f);
        ((float2*)haOut)[(size_t)ii * 64 + lane] = o;
        // attention epilogue (per-head att + psW partials -> csd)
        float a = o.x * Av.x + o.y * Av.y;
        float pp = o.x * Pv.x + o.y * Pv.y;
#pragma unroll
        for (int d = 8; d > 0; d >>= 1) {
            a += __shfl_down(a, d, 16);
            pp += __shfl_down(pp, d, 16);
        }
        float part = a * pp;                 // heads at lanes 0,16,32,48
        part += __shfl_down(part, 16, 64);
        part += __shfl_down(part, 32, 64);
        if (lane == 0) csd[ii] = part * di;  // pre-scaled by dinv[i]
    }
}

// ---------------------------------------------------------------------------
// Top-k with INLINE score: 1024 threads, one block per graph. LDS-resident
// work only (R8 lesson: no global gather phases in 32-block kernels).
// ---------------------------------------------------------------------------
__global__ __launch_bounds__(1024) void topk_kernel(
        const float* __restrict__ csd, const int* __restrict__ cnt,
        const int* __restrict__ slot, const float* __restrict__ psb,
        int nper, int k, int* __restrict__ nmap, int* __restrict__ perm,
        float* __restrict__ mult) {
    __shared__ float cs_l[NPER0];
    __shared__ float sc[NPER0];
    __shared__ unsigned ukey[NPER0];
    __shared__ unsigned hist[256];
    __shared__ unsigned wtot[4];
    __shared__ unsigned sel[2];
    __shared__ int ctr[2];
    const int g = blockIdx.x, t = threadIdx.x;
    const int gnb = g * nper;
    if (t < nper) cs_l[t] = csd[gnb + t];
    if (t == 0) { sel[0] = 0u; sel[1] = (unsigned)k; }
    __syncthreads();
    if (t < nper) {
        int ci = cnt[gnb + t];
        int c = min(ci, CAP);
        const int* srow = slot + (size_t)(gnb + t) * CAP;
        float v = 0.0f;
        for (int j = 0; j < c; j++) v += cs_l[srow[j] - gnb];
        float s = rsqrtf((float)ci + 1.0f) * (v + cs_l[t]) + psb[0];
        sc[t] = s;
        ukey[t] = enc_f(s);
    }
    __syncthreads();
    const int w4 = t >> 6, l = t & 63;
    for (int shift = 24; shift >= 0; shift -= 8) {
        if (t < 256) hist[t] = 0u;
        __syncthreads();
        const unsigned prefix = sel[0];
        const unsigned need = sel[1];
        {   // histogram with wave equal-digit pre-merge
            unsigned u = (t < nper) ? ukey[t] : 0u;
            bool inp = (t < nper) &&
                       ((shift == 24) || ((u >> (shift + 8)) == (prefix >> (shift + 8))));
            int dig = inp ? (int)((u >> shift) & 255u) : -1;
            int cv = inp ? 1 : 0;
#pragma unroll
            for (int d = 1; d < 64; d <<= 1) {
                int od = __shfl_xor(dig, d, 64);
                int oc = __shfl_xor(cv, d, 64);
                if (od == dig) cv = ((l & d) == 0) ? (cv + oc) : 0;
            }
            if (dig >= 0 && cv > 0) atomicAdd(&hist[dig], (unsigned)cv);
        }
        __syncthreads();
        unsigned h = 0, s = 0;
        if (t < 256) {
            h = hist[t];
            s = h;
#pragma unroll
            for (int off = 1; off < 64; off <<= 1) {
                unsigned v2 = __shfl_down(s, off, 64);
                if (l + off < 64) s += v2;
            }
            if (l == 0) wtot[w4] = s;
        }
        __syncthreads();
        if (t < 256) {
            unsigned add = 0;
            for (int ww = w4 + 1; ww < 4; ww++) add += wtot[ww];
            const unsigned sfx = s + add;   // #keys with digit >= t (within prefix)
            const unsigned gtr = sfx - h;   // #keys with digit >  t
            if (sfx >= need && gtr < need) {  // exactly one thread
                sel[0] = prefix | ((unsigned)t << shift);
                sel[1] = need - gtr;
            }
        }
        __syncthreads();
    }
    const unsigned T = sel[0];
    const int need2 = (int)sel[1];
    if (t == 0) { ctr[0] = 0; ctr[1] = k - need2; }
    __syncthreads();
    if (t < nper) {
        unsigned u = ukey[t];
        int newid = -1;
        if (u > T) {
            newid = atomicAdd(&ctr[0], 1);
        } else if (u == T) {
            int s2 = atomicAdd(&ctr[1], 1);
            if (s2 < k) newid = s2;
        }
        nmap[gnb + t] = (newid >= 0) ? g * k + newid : -1;
        if (newid >= 0) {
            perm[g * k + newid] = gnb + t;
            mult[g * k + newid] = tanhf(sc[t]);
        }
    }
}

// ---------------------------------------------------------------------------
// Wide fat kernel: [0,ncomp) slot compaction | [ncomp,...) pooling readout
// (8 kept nodes per block, atomics into enc-rmax/rsum).
// ---------------------------------------------------------------------------
__global__ void comp_pool(const int* __restrict__ cnt_prev,
                          const int* __restrict__ slot_prev,
                          const int* __restrict__ nmap,
                          int* __restrict__ cnt_next, int* __restrict__ slot_next,
                          const float* __restrict__ ha, const int* __restrict__ perm,
                          const float* __restrict__ mult, int ncomp, int kprev,
                          unsigned* __restrict__ rmax, float* __restrict__ rsum) {
    __shared__ float smax[128], ssum[128];
    const int t = threadIdx.x;
    if (blockIdx.x < ncomp) {
        const int w = t >> 6, lane = t & 63;
        const int b = (blockIdx.x & 31) * kprev + (blockIdx.x >> 5) * 4 + w;
        const int old = perm[b];
        const int c = min(cnt_prev[old], CAP);
        int a = -1;
        if (lane < c) a = nmap[slot_prev[(size_t)old * CAP + lane]];
        unsigned long long mk = __ballot(a >= 0);
        if (a >= 0) {
            int pos = __popcll(mk & ((1ull << lane) - 1ull));
            slot_next[(size_t)b * CAP + pos] = a;
        }
        if (lane == 0) cnt_next[b] = __popcll(mk);
        return;
    }
    const int pb = blockIdx.x - ncomp;
    const int g = pb & 31;
    const int c = pb >> 5;
    const int f = t & 127, half = t >> 7;
    const int base = g * kprev + c * 8;
    float vmax = -1e30f, vsum = 0.0f;
#pragma unroll
    for (int j0 = 0; j0 < 4; j0++) {
        int newid = base + half + j0 * 2;
        int old = perm[newid];
        float m = mult[newid];
        float v = ha[(size_t)old * FDIM + f] * m;
        vmax = fmaxf(vmax, v);
        vsum += v;
    }
    if (half) { smax[f] = vmax; ssum[f] = vsum; }
    __syncthreads();
    if (!half) {
        vmax = fmaxf(vmax, smax[f]);
        vsum += ssum[f];
        atomicMax(&rmax[g * FDIM + f], enc_f(vmax));
        atomicAdd(&rsum[g * FDIM + f], vsum);
    }
}

// ---------------------------------------------------------------------------
// Final: stage-3 pooling (block-local, 1024 threads) + MLP + log_softmax.
// ---------------------------------------------------------------------------
__global__ __launch_bounds__(1024) void pool3_mlp(
        const float* __restrict__ ha, const int* __restrict__ perm,
        const float* __restrict__ mult,
        const unsigned* __restrict__ rmax, const float* __restrict__ rsum,
        const float* __restrict__ l1W, const float* __restrict__ l1b,
        const float* __restrict__ l2W, const float* __restrict__ l2b,
        const float* __restrict__ l3W, const float* __restrict__ l3b,
        float* __restrict__ out) {
    __shared__ float pm[8][FDIM], ps[8][FDIM];
    __shared__ float sz[256], s1[128], s2[64], s3[16], red[2];
    const int g = blockIdx.x, t = threadIdx.x;
    const int f = t & 127, ch = t >> 7;
    float vmax = -1e30f, vsum = 0.0f;
#pragma unroll
    for (int j = 0; j < K3 / 8; j++) {
        int nid = g * K3 + ch + j * 8;
        int old = perm[nid];
        float m = mult[nid];
        float v = ha[(size_t)old * FDIM + f] * m;
        vmax = fmaxf(vmax, v);
        vsum += v;
    }
    pm[ch][f] = vmax;
    ps[ch][f] = vsum;
    __syncthreads();
    if (t < 128) {
        float M = pm[0][t];
#pragma unroll
        for (int c2 = 1; c2 < 8; c2++) M = fmaxf(M, pm[c2][t]);
        sz[t] = dec_f(rmax[g * FDIM + t]) + dec_f(rmax[RSEC + g * FDIM + t]) + M;
    } else if (t < 256) {
        int f2 = t - 128;
        float S = ps[0][f2];
#pragma unroll
        for (int c2 = 1; c2 < 8; c2++) S += ps[c2][f2];
        sz[t] = rsum[g * FDIM + f2] / (float)K1 + rsum[RSEC + g * FDIM + f2] / (float)K2 +
                S / (float)K3;
    }
    __syncthreads();
    if (t < 128) {
        float acc = l1b[t];
        for (int i = 0; i < 256; i++) acc = fmaf(sz[i], l1W[i * 128 + t], acc);
        s1[t] = fmaxf(acc, 0.0f);
    }
    __syncthreads();
    if (t < 64) {
        float a2 = l2b[t];
        for (int i = 0; i < 128; i++) a2 = fmaf(s1[i], l2W[i * 64 + t], a2);
        s2[t] = fmaxf(a2, 0.0f);
    }
    __syncthreads();
    if (t < 10) {
        float a3 = l3b[t];
        for (int i = 0; i < 64; i++) a3 = fmaf(s2[i], l3W[i * 10 + t], a3);
        s3[t] = a3;
    }
    __syncthreads();
    if (t == 0) {
        float m = -1e30f;
        for (int c = 0; c < 10; c++) m = fmaxf(m, s3[c]);
        float sum = 0.0f;
        for (int c = 0; c < 10; c++) sum += expf(s3[c] - m);
        red[0] = m;
        red[1] = logf(sum);
    }
    __syncthreads();
    if (t < 10) out[g * 10 + t] = s3[t] - red[0] - red[1];
}

// ---------------------------------------------------------------------------
extern "C" void kernel_launch(void* const* d_in, const int* in_sizes, int n_in,
                              void* d_out, int out_size, void* d_ws, size_t ws_size,
                              hipStream_t stream) {
    const float* x    = (const float*)d_in[0];
    const int* src0   = (const int*)d_in[1];
    const int* dst0   = (const int*)d_in[2];
    const float* W1   = (const float*)d_in[3];
    const float* b1   = (const float*)d_in[4];
    const float* A1   = (const float*)d_in[5];
    const float* ps1W = (const float*)d_in[6];
    const float* ps1b = (const float*)d_in[7];
    const float* W2   = (const float*)d_in[8];
    const float* b2   = (const float*)d_in[9];
    const float* A2   = (const float*)d_in[10];
    const float* ps2W = (const float*)d_in[11];
    const float* ps2b = (const float*)d_in[12];
    const float* W3   = (const float*)d_in[13];
    const float* b3   = (const float*)d_in[14];
    const float* A3   = (const float*)d_in[15];
    const float* ps3W = (const float*)d_in[16];
    const float* ps3b = (const float*)d_in[17];
    const float* l1W  = (const float*)d_in[18];
    const float* l1b  = (const float*)d_in[19];
    const float* l2W  = (const float*)d_in[20];
    const float* l2b  = (const float*)d_in[21];
    const float* l3W  = (const float*)d_in[22];
    const float* l3b  = (const float*)d_in[23];
    float* out = (float*)d_out;

    char* ws = (char*)d_ws;
    size_t o = 0;
    auto alloc = [&](size_t bytes) -> void* {
        void* p = ws + o;
        o += (bytes + 255) & ~(size_t)255;
        return p;
    };
    float*    ha1   = (float*)alloc((size_t)N0 * FDIM * 4);
    float*    ha2   = (float*)alloc((size_t)N1 * FDIM * 4);
    float*    ha3   = (float*)alloc((size_t)N2 * FDIM * 4);
    int*      cntA  = (int*)alloc(N0 * 4);
    int*      cntB  = (int*)alloc(N1 * 4);
    int*      cntC  = (int*)alloc(N2 * 4);
    int*      slotA = (int*)alloc((size_t)N0 * CAP * 4);
    int*      slotB = (int*)alloc((size_t)N1 * CAP * 4);
    int*      slotC = (int*)alloc((size_t)N2 * CAP * 4);
    float*    cs    = (float*)alloc(N0 * 4);
    int*      nmapA = (int*)alloc(N0 * 4);
    int*      nmapB = (int*)alloc(N1 * 4);
    int*      perm  = (int*)alloc(N1 * 4);
    float*    mult  = (float*)alloc(N1 * 4);
    unsigned* rmax  = (unsigned*)alloc(2 * RSEC * 4);
    float*    rsum  = (float*)alloc(2 * RSEC * 4);

    // ---------------- Stage 1 ----------------
    hipMemsetAsync(cntA, 0, N0 * 4, stream);
    bin_kernel<<<EBLK, 256, 0, stream>>>(src0, dst0, cntA, slotA, rmax, rsum);
    aggw_kernel<<<N0 / 8, 256, 0, stream>>>(x, nullptr, nullptr, cntA, slotA,
                                            W1, b1, A1, ps1W, ha1, cs, NPER0);
    topk_kernel<<<BGR, 1024, 0, stream>>>(cs, cntA, slotA, ps1b, NPER0, K1,
                                          nmapA, perm, mult);

    // ---------------- Stage 2 (+ stage-1 pooling readout) ----------------
    comp_pool<<<N1 / 4 + BGR * K1 / 8, 256, 0, stream>>>(
        cntA, slotA, nmapA, cntB, slotB, ha1, perm, mult, N1 / 4, K1, rmax, rsum);
    aggw_kernel<<<N1 / 8, 256, 0, stream>>>(ha1, perm, mult, cntB, slotB,
                                            W2, b2, A2, ps2W, ha2, cs, K1);
    topk_kernel<<<BGR, 1024, 0, stream>>>(cs, cntB, slotB, ps2b, K1, K2,
                                          nmapB, perm, mult);

    // ---------------- Stage 3 (+ stage-2 pooling readout) ----------------
    comp_pool<<<N2 / 4 + BGR * K2 / 8, 256, 0, stream>>>(
        cntB, slotB, nmapB, cntC, slotC, ha2, perm, mult, N2 / 4, K2,
        rmax + RSEC, rsum + RSEC);
    aggw_kernel<<<N2 / 8, 256, 0, stream>>>(ha2, perm, mult, cntC, slotC,
                                            W3, b3, A3, ps3W, ha3, cs, K2);
    topk_kernel<<<BGR, 1024, 0, stream>>>(cs, cntC, slotC, ps3b, K2, K3,
                                          nmapA /*unused*/, perm, mult);

    // ---------------- Stage-3 pooling + final MLP ----------------
    pool3_mlp<<<BGR, 1024, 0, stream>>>(ha3, perm, mult, rmax, rsum,
                                        l1W, l1b, l2W, l2b, l3W, l3b, out);

    (void)in_sizes; (void)n_in; (void)out_size; (void)ws_size;
}

// Round 12
// 225.816 us; speedup vs baseline: 1.0241x; 1.0241x over previous
//
#include <hip/hip_runtime.h>
#include <math.h>

#define BGR 32
#define NPER0 1024
#define N0 (BGR * NPER0)
#define FDIM 128
#define EDG 524288
#define EPG (EDG / BGR)   // 16384 edges per graph (contiguous by construction)
#define EBLK (EDG / 256)  // 2048 edge-parallel binning blocks
#define K1 512
#define K2 256
#define K3 128
#define N1 (BGR * K1)
#define N2 (BGR * K2)
#define CAP 64            // slots per node (Poisson(16); P(deg>64) ~ 1e-18)
#define RSEC (BGR * FDIM)

// Order-preserving float<->uint encoding (radix keys + atomicMax readout).
__device__ __forceinline__ unsigned enc_f(float v) {
    unsigned u = __float_as_uint(v);
    return (u & 0x80000000u) ? ~u : (u | 0x80000000u);
}
__device__ __forceinline__ float dec_f(unsigned u) {
    return (u & 0x80000000u) ? __uint_as_float(u ^ 0x80000000u) : __uint_as_float(~u);
}

// ---------------------------------------------------------------------------
// Edge binning (graph-swizzled: graph g's cnt/slot atomics land on XCD g%8,
// where g's aggw also runs). Blocks 0..31 also zero the readout accumulators.
// cnt pre-zeroed by hipMemsetAsync.
// ---------------------------------------------------------------------------
__global__ void bin_kernel(const int* __restrict__ src, const int* __restrict__ dst,
                           int* __restrict__ cnt, int* __restrict__ slot,
                           unsigned* __restrict__ rmax, float* __restrict__ rsum) {
    if (blockIdx.x < BGR) {  // zero readout accumulators: 32*256 == 2*RSEC
        int z = blockIdx.x * 256 + threadIdx.x;
        rmax[z] = 0u;
        rsum[z] = 0.0f;
    }
    const int g = blockIdx.x & 31, chunk = blockIdx.x >> 5;
    int e = g * EPG + chunk * 256 + threadIdx.x;
    int s = src[e];
    int d = dst[e];
    int p = atomicAdd(&cnt[d], 1);
    if (p < CAP) slot[(size_t)d * CAP + p] = s;
}

// ---------------------------------------------------------------------------
// Fused aggregate-then-project kernel (AGG(X)·W == AGG(X·W), both linear).
// R12: R10 body (one node/wave, 32-lane halves, lane = float4) + tail blocks
// [naggblk, ...) run the PREVIOUS stage's pooling readout (reads the same
// xsrc/permIn/multIn) so the pool gather hides under the aggw waves.
// ---------------------------------------------------------------------------
__global__ void aggw_kernel(const float* __restrict__ xsrc,
                            const int* __restrict__ permIn,
                            const float* __restrict__ multIn,
                            const int* __restrict__ cnt, const int* __restrict__ slot,
                            const float* __restrict__ W, const float* __restrict__ b,
                            const float* __restrict__ A, const float* __restrict__ psW,
                            float* __restrict__ haOut, float* __restrict__ csd,
                            int nper, int naggblk,
                            unsigned* __restrict__ rmax, float* __restrict__ rsum) {
    __shared__ __align__(16) float sW[4096];
    __shared__ __align__(16) float sY[4][128];
    const int t = threadIdx.x;
    if (blockIdx.x >= naggblk) {   // -------- pooling readout tail blocks -----
        float* smax = sW;
        float* ssum = sW + 128;
        const int pb = blockIdx.x - naggblk;
        const int g = pb & 31;
        const int c = pb >> 5;
        const int f = t & 127, hf = t >> 7;
        const int base = g * nper + c * 8;
        float vmax = -1e30f, vsum = 0.0f;
#pragma unroll
        for (int j0 = 0; j0 < 4; j0++) {
            int newid = base + hf + j0 * 2;
            int old = permIn[newid];
            float m = multIn[newid];
            float v = xsrc[(size_t)old * FDIM + f] * m;
            vmax = fmaxf(vmax, v);
            vsum += v;
        }
        if (hf) { smax[f] = vmax; ssum[f] = vsum; }
        __syncthreads();
        if (!hf) {
            vmax = fmaxf(vmax, smax[f]);
            vsum += ssum[f];
            atomicMax(&rmax[g * FDIM + f], enc_f(vmax));
            atomicAdd(&rsum[g * FDIM + f], vsum);
        }
        return;
    }
    // ----------------------------- aggw body --------------------------------
    const int w = t >> 6, lane = t & 63;
    const int half = lane >> 5, li = lane & 31;
    const int g = blockIdx.x & 31, chunk = blockIdx.x >> 5;
    const int i = g * nper + chunk * 4 + w;
    {   // stage W: 4096 floats via float4, coalesced
        float4* d4 = (float4*)sW;
        const float4* s4 = (const float4*)W;
        for (int q = t; q < 1024; q += 256) d4[q] = s4[q];
    }
    const int ci = cnt[i];
    const float di = rsqrtf((float)ci + 1.0f);
    const int c = min(ci, CAP);
    const float4* __restrict__ x4 = (const float4*)xsrc;
    // self term (half 0 only; half 1 coef 0)
    float selfco = di * di;
    size_t selfrow = (size_t)i;
    if (permIn) { selfrow = (size_t)permIn[i]; selfco *= multIn[i]; }
    const float sco = half ? 0.0f : selfco;
    float4 sv = x4[selfrow * 32 + li];
    float4 acc;
    acc.x = sv.x * sco; acc.y = sv.y * sco; acc.z = sv.z * sco; acc.w = sv.w * sco;
    // per-lane neighbor prefetch: row index + composed coefficient
    // (lanes >= c hold rowi=0, codv=0 -> safe dummy for the odd-c tail pair)
    int rowi = 0;
    float codv = 0.0f;
    if (lane < c) {
        int idx = slot[(size_t)i * CAP + lane];
        float dv = rsqrtf((float)cnt[idx] + 1.0f);
        if (permIn) { rowi = permIn[idx]; codv = dv * multIn[idx]; }
        else        { rowi = idx;         codv = dv; }
    }
    const int cp = (c + 1) >> 1;  // edge pairs; this half's edge = 2p + half
    int p = 0;
    for (; p + 3 < cp; p += 4) {
        int e0 = 2 * p + half;
        int s0 = __shfl(rowi, e0, 64);
        int s1 = __shfl(rowi, e0 + 2, 64);
        int s2 = __shfl(rowi, e0 + 4, 64);
        int s3 = __shfl(rowi, e0 + 6, 64);
        float c0 = __shfl(codv, e0, 64) * di;
        float c1 = __shfl(codv, e0 + 2, 64) * di;
        float c2 = __shfl(codv, e0 + 4, 64) * di;
        float c3 = __shfl(codv, e0 + 6, 64) * di;
        float4 v0 = x4[(size_t)s0 * 32 + li];
        float4 v1 = x4[(size_t)s1 * 32 + li];
        float4 v2 = x4[(size_t)s2 * 32 + li];
        float4 v3 = x4[(size_t)s3 * 32 + li];
        acc.x = fmaf(v0.x, c0, acc.x); acc.y = fmaf(v0.y, c0, acc.y);
        acc.z = fmaf(v0.z, c0, acc.z); acc.w = fmaf(v0.w, c0, acc.w);
        acc.x = fmaf(v1.x, c1, acc.x); acc.y = fmaf(v1.y, c1, acc.y);
        acc.z = fmaf(v1.z, c1, acc.z); acc.w = fmaf(v1.w, c1, acc.w);
        acc.x = fmaf(v2.x, c2, acc.x); acc.y = fmaf(v2.y, c2, acc.y);
        acc.z = fmaf(v2.z, c2, acc.z); acc.w = fmaf(v2.w, c2, acc.w);
        acc.x = fmaf(v3.x, c3, acc.x); acc.y = fmaf(v3.y, c3, acc.y);
        acc.z = fmaf(v3.z, c3, acc.z); acc.w = fmaf(v3.w, c3, acc.w);
    }
    for (; p < cp; p++) {
        int e = 2 * p + half;
        int s = __shfl(rowi, e, 64);
        float co = __shfl(codv, e, 64) * di;
        float4 v = x4[(size_t)s * 32 + li];
        acc.x = fmaf(v.x, co, acc.x); acc.y = fmaf(v.y, co, acc.y);
        acc.z = fmaf(v.z, co, acc.z); acc.w = fmaf(v.w, co, acc.w);
    }
    // combine even/odd halves
    acc.x += __shfl_xor(acc.x, 32, 64);
    acc.y += __shfl_xor(acc.y, 32, 64);
    acc.z += __shfl_xor(acc.z, 32, 64);
    acc.w += __shfl_xor(acc.w, 32, 64);
    if (half == 0) *(float4*)(&sY[w][li * 4]) = acc;
    __syncthreads();
    // dense per-head W-multiply (sY broadcast reads, sW conflict-free)
    const int f0 = 2 * lane;           // output features f0, f0+1 (same head)
    const int h = f0 >> 5, e0h = f0 & 31;
    const float* yp = sY[w] + h * 32;
    const float* wrow = sW + h * 1024 + e0h;
    float2 bb = ((const float2*)b)[lane];
    float ax = bb.x, ay = bb.y;
#pragma unroll
    for (int d = 0; d < 32; d++) {
        float yv = yp[d];                                  // broadcast read
        float2 wv = *(const float2*)(wrow + d * 32);       // conflict-free
        ax = fmaf(yv, wv.x, ax);
        ay = fmaf(yv, wv.y, ay);
    }
    float2 o;
    o.x = fmaxf(ax, 0.0f);
    o.y = fmaxf(ay, 0.0f);
    ((float2*)haOut)[(size_t)i * 64 + lane] = o;
    // attention epilogue (per-head att + psW partials -> csd)
    float2 Av = ((const float2*)A)[lane];
    float2 Pv = ((const float2*)psW)[lane];
    float a = o.x * Av.x + o.y * Av.y;
    float pp = o.x * Pv.x + o.y * Pv.y;
#pragma unroll
    for (int d = 8; d > 0; d >>= 1) {
        a += __shfl_down(a, d, 16);
        pp += __shfl_down(pp, d, 16);
    }
    float part = a * pp;                 // heads at lanes 0,16,32,48
    part += __shfl_down(part, 16, 64);
    part += __shfl_down(part, 32, 64);
    if (lane == 0) csd[i] = part * di;   // pre-scaled by dinv[i]
}

// ---------------------------------------------------------------------------
// Standalone slot compaction (wide): wave per kept node; remap prev slots via
// nmap, ballot-compact. No atomics.
// ---------------------------------------------------------------------------
__global__ void comp_kernel(const int* __restrict__ cnt_prev,
                            const int* __restrict__ slot_prev,
                            const int* __restrict__ nmap,
                            const int* __restrict__ perm,
                            int* __restrict__ cnt_next, int* __restrict__ slot_next,
                            int knext) {
    const int t = threadIdx.x;
    const int w = t >> 6, lane = t & 63;
    const int b = (blockIdx.x & 31) * knext + (blockIdx.x >> 5) * 4 + w;
    const int old = perm[b];
    const int c = min(cnt_prev[old], CAP);
    int a = -1;
    if (lane < c) a = nmap[slot_prev[(size_t)old * CAP + lane]];
    unsigned long long mk = __ballot(a >= 0);
    if (a >= 0) {
        int pos = __popcll(mk & ((1ull << lane) - 1ull));
        slot_next[(size_t)b * CAP + pos] = a;
    }
    if (lane == 0) cnt_next[b] = __popcll(mk);
}

// ---------------------------------------------------------------------------
// Top-k with INLINE score: 1024 threads, one block per graph. LDS-resident
// work only (R8 lesson: no global gather phases in 32-block kernels).
// ---------------------------------------------------------------------------
__global__ __launch_bounds__(1024) void topk_kernel(
        const float* __restrict__ csd, const int* __restrict__ cnt,
        const int* __restrict__ slot, const float* __restrict__ psb,
        int nper, int k, int* __restrict__ nmap, int* __restrict__ perm,
        float* __restrict__ mult) {
    __shared__ float cs_l[NPER0];
    __shared__ float sc[NPER0];
    __shared__ unsigned ukey[NPER0];
    __shared__ unsigned hist[256];
    __shared__ unsigned wtot[4];
    __shared__ unsigned sel[2];
    __shared__ int ctr[2];
    const int g = blockIdx.x, t = threadIdx.x;
    const int gnb = g * nper;
    if (t < nper) cs_l[t] = csd[gnb + t];
    if (t == 0) { sel[0] = 0u; sel[1] = (unsigned)k; }
    __syncthreads();
    if (t < nper) {
        int ci = cnt[gnb + t];
        int c = min(ci, CAP);
        const int* srow = slot + (size_t)(gnb + t) * CAP;
        float v = 0.0f;
        for (int j = 0; j < c; j++) v += cs_l[srow[j] - gnb];
        float s = rsqrtf((float)ci + 1.0f) * (v + cs_l[t]) + psb[0];
        sc[t] = s;
        ukey[t] = enc_f(s);
    }
    __syncthreads();
    const int w4 = t >> 6, l = t & 63;
    for (int shift = 24; shift >= 0; shift -= 8) {
        if (t < 256) hist[t] = 0u;
        __syncthreads();
        const unsigned prefix = sel[0];
        const unsigned need = sel[1];
        {   // histogram with wave equal-digit pre-merge
            unsigned u = (t < nper) ? ukey[t] : 0u;
            bool inp = (t < nper) &&
                       ((shift == 24) || ((u >> (shift + 8)) == (prefix >> (shift + 8))));
            int dig = inp ? (int)((u >> shift) & 255u) : -1;
            int cv = inp ? 1 : 0;
#pragma unroll
            for (int d = 1; d < 64; d <<= 1) {
                int od = __shfl_xor(dig, d, 64);
                int oc = __shfl_xor(cv, d, 64);
                if (od == dig) cv = ((l & d) == 0) ? (cv + oc) : 0;
            }
            if (dig >= 0 && cv > 0) atomicAdd(&hist[dig], (unsigned)cv);
        }
        __syncthreads();
        unsigned h = 0, s = 0;
        if (t < 256) {
            h = hist[t];
            s = h;
#pragma unroll
            for (int off = 1; off < 64; off <<= 1) {
                unsigned v2 = __shfl_down(s, off, 64);
                if (l + off < 64) s += v2;
            }
            if (l == 0) wtot[w4] = s;
        }
        __syncthreads();
        if (t < 256) {
            unsigned add = 0;
            for (int ww = w4 + 1; ww < 4; ww++) add += wtot[ww];
            const unsigned sfx = s + add;   // #keys with digit >= t (within prefix)
            const unsigned gtr = sfx - h;   // #keys with digit >  t
            if (sfx >= need && gtr < need) {  // exactly one thread
                sel[0] = prefix | ((unsigned)t << shift);
                sel[1] = need - gtr;
            }
        }
        __syncthreads();
    }
    const unsigned T = sel[0];
    const int need2 = (int)sel[1];
    if (t == 0) { ctr[0] = 0; ctr[1] = k - need2; }
    __syncthreads();
    if (t < nper) {
        unsigned u = ukey[t];
        int newid = -1;
        if (u > T) {
            newid = atomicAdd(&ctr[0], 1);
        } else if (u == T) {
            int s2 = atomicAdd(&ctr[1], 1);
            if (s2 < k) newid = s2;
        }
        nmap[gnb + t] = (newid >= 0) ? g * k + newid : -1;
        if (newid >= 0) {
            perm[g * k + newid] = gnb + t;
            mult[g * k + newid] = tanhf(sc[t]);
        }
    }
}

// ---------------------------------------------------------------------------
// Final fused kernel: topk3 (radix select over K2=256 scores, perm/mult in
// LDS only) + stage-3 pooling + MLP + log_softmax. One block per graph.
// ---------------------------------------------------------------------------
__global__ __launch_bounds__(1024) void topk3_mlp(
        const float* __restrict__ csd, const int* __restrict__ cnt,
        const int* __restrict__ slot, const float* __restrict__ psb,
        const float* __restrict__ ha,
        const unsigned* __restrict__ rmax, const float* __restrict__ rsum,
        const float* __restrict__ l1W, const float* __restrict__ l1b,
        const float* __restrict__ l2W, const float* __restrict__ l2b,
        const float* __restrict__ l3W, const float* __restrict__ l3b,
        float* __restrict__ out) {
    __shared__ float cs_l[K2];
    __shared__ float sc[K2];
    __shared__ unsigned ukey[K2];
    __shared__ unsigned hist[256];
    __shared__ unsigned wtot[4];
    __shared__ unsigned sel[2];
    __shared__ int ctr[2];
    __shared__ int perm_l[K3];
    __shared__ float mult_l[K3];
    __shared__ float pm[8][FDIM], ps[8][FDIM];
    __shared__ float sz[256], s1[128], s2[64], s3[16], red[2];
    const int g = blockIdx.x, t = threadIdx.x;
    const int gnb = g * K2;
    if (t < K2) cs_l[t] = csd[gnb + t];
    if (t == 0) { sel[0] = 0u; sel[1] = (unsigned)K3; }
    __syncthreads();
    if (t < K2) {   // inline score
        int ci = cnt[gnb + t];
        int c = min(ci, CAP);
        const int* srow = slot + (size_t)(gnb + t) * CAP;
        float v = 0.0f;
        for (int j = 0; j < c; j++) v += cs_l[srow[j] - gnb];
        float s = rsqrtf((float)ci + 1.0f) * (v + cs_l[t]) + psb[0];
        sc[t] = s;
        ukey[t] = enc_f(s);
    }
    __syncthreads();
    const int w4 = t >> 6, l = t & 63;
    for (int shift = 24; shift >= 0; shift -= 8) {
        if (t < 256) hist[t] = 0u;
        __syncthreads();
        const unsigned prefix = sel[0];
        const unsigned need = sel[1];
        {
            unsigned u = (t < K2) ? ukey[t] : 0u;
            bool inp = (t < K2) &&
                       ((shift == 24) || ((u >> (shift + 8)) == (prefix >> (shift + 8))));
            int dig = inp ? (int)((u >> shift) & 255u) : -1;
            int cv = inp ? 1 : 0;
#pragma unroll
            for (int d = 1; d < 64; d <<= 1) {
                int od = __shfl_xor(dig, d, 64);
                int oc = __shfl_xor(cv, d, 64);
                if (od == dig) cv = ((l & d) == 0) ? (cv + oc) : 0;
            }
            if (dig >= 0 && cv > 0) atomicAdd(&hist[dig], (unsigned)cv);
        }
        __syncthreads();
        unsigned h = 0, s = 0;
        if (t < 256) {
            h = hist[t];
            s = h;
#pragma unroll
            for (int off = 1; off < 64; off <<= 1) {
                unsigned v2 = __shfl_down(s, off, 64);
                if (l + off < 64) s += v2;
            }
            if (l == 0) wtot[w4] = s;
        }
        __syncthreads();
        if (t < 256) {
            unsigned add = 0;
            for (int ww = w4 + 1; ww < 4; ww++) add += wtot[ww];
            const unsigned sfx = s + add;
            const unsigned gtr = sfx - h;
            if (sfx >= need && gtr < need) {
                sel[0] = prefix | ((unsigned)t << shift);
                sel[1] = need - gtr;
            }
        }
        __syncthreads();
    }
    const unsigned T = sel[0];
    const int need2 = (int)sel[1];
    if (t == 0) { ctr[0] = 0; ctr[1] = K3 - need2; }
    __syncthreads();
    if (t < K2) {
        unsigned u = ukey[t];
        int newid = -1;
        if (u > T) {
            newid = atomicAdd(&ctr[0], 1);
        } else if (u == T) {
            int s2 = atomicAdd(&ctr[1], 1);
            if (s2 < K3) newid = s2;
        }
        if (newid >= 0) {
            perm_l[newid] = gnb + t;
            mult_l[newid] = tanhf(sc[t]);
        }
    }
    __syncthreads();
    // ---- stage-3 pooling (perm/mult from LDS) ----
    {
        const int f = t & 127, ch = t >> 7;
        float vmax = -1e30f, vsum = 0.0f;
#pragma unroll
        for (int j = 0; j < K3 / 8; j++) {
            int lid = ch + j * 8;
            int old = perm_l[lid];
            float m = mult_l[lid];
            float v = ha[(size_t)old * FDIM + f] * m;
            vmax = fmaxf(vmax, v);
            vsum += v;
        }
        pm[ch][f] = vmax;
        ps[ch][f] = vsum;
    }
    __syncthreads();
    if (t < 128) {
        float M = pm[0][t];
#pragma unroll
        for (int c2 = 1; c2 < 8; c2++) M = fmaxf(M, pm[c2][t]);
        sz[t] = dec_f(rmax[g * FDIM + t]) + dec_f(rmax[RSEC + g * FDIM + t]) + M;
    } else if (t < 256) {
        int f2 = t - 128;
        float S = ps[0][f2];
#pragma unroll
        for (int c2 = 1; c2 < 8; c2++) S += ps[c2][f2];
        sz[t] = rsum[g * FDIM + f2] / (float)K1 + rsum[RSEC + g * FDIM + f2] / (float)K2 +
                S / (float)K3;
    }
    __syncthreads();
    if (t < 128) {
        float acc = l1b[t];
        for (int i = 0; i < 256; i++) acc = fmaf(sz[i], l1W[i * 128 + t], acc);
        s1[t] = fmaxf(acc, 0.0f);
    }
    __syncthreads();
    if (t < 64) {
        float a2 = l2b[t];
        for (int i = 0; i < 128; i++) a2 = fmaf(s1[i], l2W[i * 64 + t], a2);
        s2[t] = fmaxf(a2, 0.0f);
    }
    __syncthreads();
    if (t < 10) {
        float a3 = l3b[t];
        for (int i = 0; i < 64; i++) a3 = fmaf(s2[i], l3W[i * 10 + t], a3);
        s3[t] = a3;
    }
    __syncthreads();
    if (t == 0) {
        float m = -1e30f;
        for (int c = 0; c < 10; c++) m = fmaxf(m, s3[c]);
        float sum = 0.0f;
        for (int c = 0; c < 10; c++) sum += expf(s3[c] - m);
        red[0] = m;
        red[1] = logf(sum);
    }
    __syncthreads();
    if (t < 10) out[g * 10 + t] = s3[t] - red[0] - red[1];
}

// ---------------------------------------------------------------------------
extern "C" void kernel_launch(void* const* d_in, const int* in_sizes, int n_in,
                              void* d_out, int out_size, void* d_ws, size_t ws_size,
                              hipStream_t stream) {
    const float* x    = (const float*)d_in[0];
    const int* src0   = (const int*)d_in[1];
    const int* dst0   = (const int*)d_in[2];
    const float* W1   = (const float*)d_in[3];
    const float* b1   = (const float*)d_in[4];
    const float* A1   = (const float*)d_in[5];
    const float* ps1W = (const float*)d_in[6];
    const float* ps1b = (const float*)d_in[7];
    const float* W2   = (const float*)d_in[8];
    const float* b2   = (const float*)d_in[9];
    const float* A2   = (const float*)d_in[10];
    const float* ps2W = (const float*)d_in[11];
    const float* ps2b = (const float*)d_in[12];
    const float* W3   = (const float*)d_in[13];
    const float* b3   = (const float*)d_in[14];
    const float* A3   = (const float*)d_in[15];
    const float* ps3W = (const float*)d_in[16];
    const float* ps3b = (const float*)d_in[17];
    const float* l1W  = (const float*)d_in[18];
    const float* l1b  = (const float*)d_in[19];
    const float* l2W  = (const float*)d_in[20];
    const float* l2b  = (const float*)d_in[21];
    const float* l3W  = (const float*)d_in[22];
    const float* l3b  = (const float*)d_in[23];
    float* out = (float*)d_out;

    char* ws = (char*)d_ws;
    size_t o = 0;
    auto alloc = [&](size_t bytes) -> void* {
        void* p = ws + o;
        o += (bytes + 255) & ~(size_t)255;
        return p;
    };
    float*    ha1   = (float*)alloc((size_t)N0 * FDIM * 4);
    float*    ha2   = (float*)alloc((size_t)N1 * FDIM * 4);
    float*    ha3   = (float*)alloc((size_t)N2 * FDIM * 4);
    int*      cntA  = (int*)alloc(N0 * 4);
    int*      cntB  = (int*)alloc(N1 * 4);
    int*      cntC  = (int*)alloc(N2 * 4);
    int*      slotA = (int*)alloc((size_t)N0 * CAP * 4);
    int*      slotB = (int*)alloc((size_t)N1 * CAP * 4);
    int*      slotC = (int*)alloc((size_t)N2 * CAP * 4);
    float*    cs    = (float*)alloc(N0 * 4);
    int*      nmapA = (int*)alloc(N0 * 4);
    int*      nmapB = (int*)alloc(N1 * 4);
    int*      perm  = (int*)alloc(N1 * 4);
    float*    mult  = (float*)alloc(N1 * 4);
    unsigned* rmax  = (unsigned*)alloc(2 * RSEC * 4);
    float*    rsum  = (float*)alloc(2 * RSEC * 4);

    // ---------------- Stage 1 ----------------
    hipMemsetAsync(cntA, 0, N0 * 4, stream);
    bin_kernel<<<EBLK, 256, 0, stream>>>(src0, dst0, cntA, slotA, rmax, rsum);
    aggw_kernel<<<N0 / 4, 256, 0, stream>>>(x, nullptr, nullptr, cntA, slotA,
                                            W1, b1, A1, ps1W, ha1, cs, NPER0,
                                            N0 / 4, nullptr, nullptr);
    topk_kernel<<<BGR, 1024, 0, stream>>>(cs, cntA, slotA, ps1b, NPER0, K1,
                                          nmapA, perm, mult);

    // ---------------- Stage 2 (stage-1 pool rides aggw2) ----------------
    comp_kernel<<<N1 / 4, 256, 0, stream>>>(cntA, slotA, nmapA, perm, cntB, slotB, K1);
    aggw_kernel<<<N1 / 4 + BGR * K1 / 8, 256, 0, stream>>>(
        ha1, perm, mult, cntB, slotB, W2, b2, A2, ps2W, ha2, cs, K1,
        N1 / 4, rmax, rsum);
    topk_kernel<<<BGR, 1024, 0, stream>>>(cs, cntB, slotB, ps2b, K1, K2,
                                          nmapB, perm, mult);

    // ---------------- Stage 3 (stage-2 pool rides aggw3) ----------------
    comp_kernel<<<N2 / 4, 256, 0, stream>>>(cntB, slotB, nmapB, perm, cntC, slotC, K2);
    aggw_kernel<<<N2 / 4 + BGR * K2 / 8, 256, 0, stream>>>(
        ha2, perm, mult, cntC, slotC, W3, b3, A3, ps3W, ha3, cs, K2,
        N2 / 4, rmax + RSEC, rsum + RSEC);

    // ---------------- topk3 + stage-3 pooling + final MLP (fused) ----------
    topk3_mlp<<<BGR, 1024, 0, stream>>>(cs, cntC, slotC, ps3b, ha3, rmax, rsum,
                                        l1W, l1b, l2W, l2b, l3W, l3b, out);

    (void)in_sizes; (void)n_in; (void)out_size; (void)ws_size;
}